// Round 1
// baseline (674.367 us; speedup 1.0000x reference)
//
#include <hip/hip_runtime.h>

// SimpleNonLocal: B=8, C=256, H=W=168, 3x3 grid of 56x56 patches, d=32.
// out = x + phi( Bc @ ((Bc^T Dn)/n) ) with Bc = Bn - mean(Bn), Bn = W_B x, Dn = W_D x.
// Restructured:
//   Bn[p,j,d], Dn[p,j,d]  (1x1 conv, patch-independent)
//   S[d,e]  = sum_j Bn[j,d] Dn[j,e];  T = S/n - mB (x) mD
//   G[c,d]  = sum_e W_phi[c,e] T[d,e];  h[c] = sum_d mB[d] G[c,d]
//   out[c,j] = x[c,j] + sum_d Bn[j,d] G[c,d] - h[c]

#define BB    8
#define CC    256
#define HH    168
#define WWs   168
#define HWs   28224       // 168*168
#define PH    56
#define NPOS  3136        // 56*56
#define NP    72          // 8 * 9 patches
#define DD    32

// workspace layout (float offsets)
#define OFF_WBT 0                         // 256*32
#define OFF_WDT (OFF_WBT + 8192)          // 256*32
#define OFF_BN  (OFF_WDT + 8192)          // 72*32*3136 = 7225344
#define OFF_DN  (OFF_BN + 7225344)
#define OFF_SP  (OFF_DN + 7225344)        // 72*8*1024
#define OFF_MBP (OFF_SP + 72*8*1024)      // 72*8*32
#define OFF_MDP (OFF_MBP + 72*8*32)       // 72*8*32
#define OFF_G   (OFF_MDP + 72*8*32)       // 72*256*32
#define OFF_H   (OFF_G + 72*256*32)       // 72*256
// total = 15,702,016 floats = 62.8 MB of d_ws

// ---- kernel 0: transpose W_B, W_D ([32][256] -> [256][32]) so that the
// per-channel weight rows are contiguous => wave-uniform s_load in kA.
__global__ void ktrans(const float* __restrict__ wb, const float* __restrict__ wd,
                       float* __restrict__ wbt, float* __restrict__ wdt) {
    const int c = threadIdx.x;  // 256 threads
    #pragma unroll
    for (int d = 0; d < DD; ++d) {
        wbt[c * DD + d] = wb[d * CC + c];
        wdt[c * DD + d] = wd[d * CC + c];
    }
}

// ---- kernel A: Bn/Dn projection. grid (13, 72), 256 thr. thread <-> patch pos j.
// Weight reads are block-uniform (scalar loads); x reads coalesced (<=2 row
// segments per wave); Bn/Dn stores [p][d][j] coalesced per d.
__global__ __launch_bounds__(256) void kA(const float* __restrict__ x,
                                          const float* __restrict__ wbt,
                                          const float* __restrict__ wdt,
                                          float* __restrict__ bn,
                                          float* __restrict__ dn) {
    const int jb = blockIdx.x;      // 0..12
    const int p  = blockIdx.y;      // 0..71
    const int t  = threadIdx.x;
    const int j  = jb * 256 + t;
    const bool valid = j < NPOS;
    const int jc = valid ? j : (NPOS - 1);
    const int b  = p / 9;
    const int gy = (p % 9) / 3;
    const int gx = p % 3;
    const int iy = jc / PH;
    const int ix = jc % PH;
    const long base = (long)b * CC * HWs + (long)(gy * PH + iy) * WWs + (gx * PH + ix);

    float accB[DD], accD[DD];
    #pragma unroll
    for (int d = 0; d < DD; ++d) { accB[d] = 0.f; accD[d] = 0.f; }

    const float* xc = x + base;
    const float* wbp = wbt;
    const float* wdp = wdt;
    #pragma unroll 4
    for (int c = 0; c < CC; ++c) {
        const float xv = *xc;
        #pragma unroll
        for (int d = 0; d < DD; ++d) {
            accB[d] = fmaf(xv, wbp[d], accB[d]);
            accD[d] = fmaf(xv, wdp[d], accD[d]);
        }
        xc += HWs; wbp += DD; wdp += DD;
    }

    if (valid) {
        float* bp = bn + (long)p * DD * NPOS + j;
        float* dp = dn + (long)p * DD * NPOS + j;
        #pragma unroll
        for (int d = 0; d < DD; ++d) {
            bp[(long)d * NPOS] = accB[d];
            dp[(long)d * NPOS] = accD[d];
        }
    }
}

// ---- kernel B1: partial S = Bn^T Dn (+ mB/mD partial sums) per (patch, j-eighth).
// grid (8, 72), 256 thr; thread owns a 2x2 (d,e) tile. LDS stride 34 => no bank
// conflicts on float2 reads.
#define B1_TJ 56
__global__ __launch_bounds__(256) void kB1(const float* __restrict__ bn,
                                           const float* __restrict__ dn,
                                           float* __restrict__ spart,
                                           float* __restrict__ mbp,
                                           float* __restrict__ mdp) {
    const int qb = blockIdx.x;  // 0..7
    const int p  = blockIdx.y;
    const int t  = threadIdx.x;
    const int j0 = qb * 392;    // 8 * 392 = 3136
    __shared__ float Bt[B1_TJ][34];
    __shared__ float Dt[B1_TJ][34];
    const int d2 = (t >> 4) << 1;   // 0,2,...,30
    const int e2 = (t & 15) << 1;   // 0,2,...,30
    float a00 = 0, a01 = 0, a10 = 0, a11 = 0;
    float mb0 = 0, mb1 = 0, md0 = 0, md1 = 0;

    const long pbase = (long)p * DD * NPOS;
    for (int tt = 0; tt < 7; ++tt) {
        const int jt = j0 + tt * B1_TJ;
        __syncthreads();
        for (int i = t; i < B1_TJ * DD; i += 256) {
            const int d  = i / B1_TJ;
            const int jj = i % B1_TJ;
            Bt[jj][d] = bn[pbase + (long)d * NPOS + jt + jj];
            Dt[jj][d] = dn[pbase + (long)d * NPOS + jt + jj];
        }
        __syncthreads();
        #pragma unroll 4
        for (int jj = 0; jj < B1_TJ; ++jj) {
            const float2 bv = *(const float2*)&Bt[jj][d2];
            const float2 dv = *(const float2*)&Dt[jj][e2];
            a00 = fmaf(bv.x, dv.x, a00);
            a01 = fmaf(bv.x, dv.y, a01);
            a10 = fmaf(bv.y, dv.x, a10);
            a11 = fmaf(bv.y, dv.y, a11);
            if (e2 == 0) { mb0 += bv.x; mb1 += bv.y; }
            if (d2 == 0) { md0 += dv.x; md1 += dv.y; }
        }
    }

    float* sp = spart + (long)(p * 8 + qb) * 1024;
    sp[(d2    ) * DD + e2    ] = a00;
    sp[(d2    ) * DD + e2 + 1] = a01;
    sp[(d2 + 1) * DD + e2    ] = a10;
    sp[(d2 + 1) * DD + e2 + 1] = a11;
    if (e2 == 0) { mbp[(p * 8 + qb) * DD + d2] = mb0; mbp[(p * 8 + qb) * DD + d2 + 1] = mb1; }
    if (d2 == 0) { mdp[(p * 8 + qb) * DD + e2] = md0; mdp[(p * 8 + qb) * DD + e2 + 1] = md1; }
}

// ---- kernel B2: reduce partials -> T -> G, h. grid (72), 256 thr.
__global__ __launch_bounds__(256) void kB2(const float* __restrict__ wphi,
                                           const float* __restrict__ spart,
                                           const float* __restrict__ mbp,
                                           const float* __restrict__ mdp,
                                           float* __restrict__ gout,
                                           float* __restrict__ hout) {
    const int p = blockIdx.x;
    const int t = threadIdx.x;
    __shared__ float Tm[DD][DD + 1];
    __shared__ float mbs[DD], mds[DD];

    if (t < DD) {
        float s1 = 0, s2 = 0;
        for (int q = 0; q < 8; ++q) {
            s1 += mbp[(p * 8 + q) * DD + t];
            s2 += mdp[(p * 8 + q) * DD + t];
        }
        mbs[t] = s1; mds[t] = s2;
    }
    __syncthreads();

    const float invn = 1.0f / (float)NPOS;
    {
        float4 s = make_float4(0.f, 0.f, 0.f, 0.f);
        for (int q = 0; q < 8; ++q) {
            const float4 v = *(const float4*)&spart[(long)(p * 8 + q) * 1024 + t * 4];
            s.x += v.x; s.y += v.y; s.z += v.z; s.w += v.w;
        }
        const int idx = t * 4;
        const int d = idx >> 5;
        const int e = idx & 31;
        const float mbd = mbs[d] * invn;
        Tm[d][e    ] = s.x * invn - mbd * (mds[e    ] * invn);
        Tm[d][e + 1] = s.y * invn - mbd * (mds[e + 1] * invn);
        Tm[d][e + 2] = s.z * invn - mbd * (mds[e + 2] * invn);
        Tm[d][e + 3] = s.w * invn - mbd * (mds[e + 3] * invn);
    }
    __syncthreads();

    // per-thread: one output channel c
    const int c = t;
    float wp[DD];
    #pragma unroll
    for (int e = 0; e < DD; ++e) wp[e] = wphi[c * DD + e];
    float h = 0.f;
    float* gp = gout + ((long)p * CC + c) * DD;
    #pragma unroll 4
    for (int d = 0; d < DD; ++d) {
        float g = 0.f;
        #pragma unroll
        for (int e = 0; e < DD; ++e) g = fmaf(wp[e], Tm[d][e], g);
        gp[d] = g;
        h = fmaf(mbs[d] * invn, g, h);
    }
    hout[p * CC + c] = h;
}

// ---- kernel C: out = x + Bn*G^T - h. grid (13, 72), 256 thr.
// Bn row in 32 VGPRs; G/h rows block-uniform => scalar loads; x/out coalesced.
__global__ __launch_bounds__(256) void kC(const float* __restrict__ x,
                                          const float* __restrict__ bn,
                                          const float* __restrict__ gbuf,
                                          const float* __restrict__ hbuf,
                                          float* __restrict__ out) {
    const int jb = blockIdx.x;
    const int p  = blockIdx.y;
    const int t  = threadIdx.x;
    const int j  = jb * 256 + t;
    const bool valid = j < NPOS;
    const int jc = valid ? j : (NPOS - 1);
    const int b  = p / 9;
    const int gy = (p % 9) / 3;
    const int gx = p % 3;
    const int iy = jc / PH;
    const int ix = jc % PH;
    const long base = (long)b * CC * HWs + (long)(gy * PH + iy) * WWs + (gx * PH + ix);

    float bnv[DD];
    const float* bp = bn + (long)p * DD * NPOS + jc;
    #pragma unroll
    for (int d = 0; d < DD; ++d) bnv[d] = bp[(long)d * NPOS];

    const float* gp = gbuf + (long)p * CC * DD;
    const float* hp = hbuf + p * CC;
    const float* xc = x + base;
    float* oc = out + base;
    #pragma unroll 4
    for (int c = 0; c < CC; ++c) {
        float acc = -hp[c];
        #pragma unroll
        for (int d = 0; d < DD; ++d) acc = fmaf(bnv[d], gp[d], acc);
        if (valid) *oc = *xc + acc;
        gp += DD; xc += HWs; oc += HWs;
    }
}

extern "C" void kernel_launch(void* const* d_in, const int* in_sizes, int n_in,
                              void* d_out, int out_size, void* d_ws, size_t ws_size,
                              hipStream_t stream) {
    const float* x    = (const float*)d_in[0];
    const float* wb   = (const float*)d_in[1];
    const float* wd   = (const float*)d_in[2];
    const float* wphi = (const float*)d_in[3];
    float* ws = (float*)d_ws;

    float* wbt = ws + OFF_WBT;
    float* wdt = ws + OFF_WDT;
    float* bnp = ws + OFF_BN;
    float* dnp = ws + OFF_DN;
    float* sp  = ws + OFF_SP;
    float* mbp = ws + OFF_MBP;
    float* mdp = ws + OFF_MDP;
    float* gb  = ws + OFF_G;
    float* hb  = ws + OFF_H;

    hipLaunchKernelGGL(ktrans, dim3(1), dim3(256), 0, stream, wb, wd, wbt, wdt);
    hipLaunchKernelGGL(kA, dim3(13, 72), dim3(256), 0, stream, x, wbt, wdt, bnp, dnp);
    hipLaunchKernelGGL(kB1, dim3(8, 72), dim3(256), 0, stream, bnp, dnp, sp, mbp, mdp);
    hipLaunchKernelGGL(kB2, dim3(72), dim3(256), 0, stream, wphi, sp, mbp, mdp, gb, hb);
    hipLaunchKernelGGL(kC, dim3(13, 72), dim3(256), 0, stream, x, bnp, gb, hb, (float*)d_out);
}

// Round 4
// 592.683 us; speedup vs baseline: 1.1378x; 1.1378x over previous
//
#include <hip/hip_runtime.h>

// SimpleNonLocal: B=8, C=256, H=W=168, 3x3 grid of 56x56 patches, d=32.
// out = x + phi( Bc @ ((Bc^T Dn)/n) ) with Bc = Bn - mean(Bn), Bn = W_B x, Dn = W_D x.
// Restructured:
//   Bn[p,j,d], Dn[p,j,d]  (1x1 conv, patch-independent)
//   S[d,e]  = sum_j Bn[j,d] Dn[j,e];  T = S/n - mB (x) mD
//   G[c,d]  = sum_e W_phi[c,e] T[d,e];  h[c] = sum_d mB[d] G[c,d]
//   out[c,j] = x[c,j] + sum_d Bn[j,d] G[c,d] - h[c]
//
// R2 change (resubmitted R3, R4 — broker timeouts, never measured): kA/kC were
// latency-bound (VALUBusy 27%, hbm 14%, occupancy grid-limited at ~3.6
// waves/SIMD). Stage 8 channels of x into registers per step -> 8
// outstanding strided loads per wave, then a 512-FMA burst.

#define BB    8
#define CC    256
#define HH    168
#define WWs   168
#define HWs   28224       // 168*168
#define PH    56
#define NPOS  3136        // 56*56
#define NP    72          // 8 * 9 patches
#define DD    32

// workspace layout (float offsets)
#define OFF_WBT 0                         // 256*32
#define OFF_WDT (OFF_WBT + 8192)          // 256*32
#define OFF_BN  (OFF_WDT + 8192)          // 72*32*3136 = 7225344
#define OFF_DN  (OFF_BN + 7225344)
#define OFF_SP  (OFF_DN + 7225344)        // 72*8*1024
#define OFF_MBP (OFF_SP + 72*8*1024)      // 72*8*32
#define OFF_MDP (OFF_MBP + 72*8*32)       // 72*8*32
#define OFF_G   (OFF_MDP + 72*8*32)       // 72*256*32
#define OFF_H   (OFF_G + 72*256*32)       // 72*256
// total = 15,702,016 floats = 62.8 MB of d_ws

// ---- kernel 0: transpose W_B, W_D ([32][256] -> [256][32]) so that the
// per-channel weight rows are contiguous => wave-uniform s_load in kA.
__global__ void ktrans(const float* __restrict__ wb, const float* __restrict__ wd,
                       float* __restrict__ wbt, float* __restrict__ wdt) {
    const int c = threadIdx.x;  // 256 threads
    #pragma unroll
    for (int d = 0; d < DD; ++d) {
        wbt[c * DD + d] = wb[d * CC + c];
        wdt[c * DD + d] = wd[d * CC + c];
    }
}

// ---- kernel A: Bn/Dn projection. grid (13, 72), 256 thr. thread <-> patch pos j.
// 8-deep register staging of x: 8 independent strided loads issued back-to-back,
// then 8*64 FMA burst. Weight reads block-uniform (s_load).
__global__ __launch_bounds__(256) void kA(const float* __restrict__ x,
                                          const float* __restrict__ wbt,
                                          const float* __restrict__ wdt,
                                          float* __restrict__ bn,
                                          float* __restrict__ dn) {
    const int jb = blockIdx.x;      // 0..12
    const int p  = blockIdx.y;      // 0..71
    const int t  = threadIdx.x;
    const int j  = jb * 256 + t;
    const bool valid = j < NPOS;
    const int jc = valid ? j : (NPOS - 1);
    const int b  = p / 9;
    const int gy = (p % 9) / 3;
    const int gx = p % 3;
    const int iy = jc / PH;
    const int ix = jc % PH;
    const long base = (long)b * CC * HWs + (long)(gy * PH + iy) * WWs + (gx * PH + ix);

    float accB[DD], accD[DD];
    #pragma unroll
    for (int d = 0; d < DD; ++d) { accB[d] = 0.f; accD[d] = 0.f; }

    const float* xc = x + base;
    #pragma unroll 1
    for (int c0 = 0; c0 < CC; c0 += 8) {
        float xv[8];
        #pragma unroll
        for (int u = 0; u < 8; ++u) xv[u] = xc[(long)u * HWs];
        #pragma unroll
        for (int u = 0; u < 8; ++u) {
            const float* wbp = wbt + (c0 + u) * DD;
            const float* wdp = wdt + (c0 + u) * DD;
            #pragma unroll
            for (int d = 0; d < DD; ++d) {
                accB[d] = fmaf(xv[u], wbp[d], accB[d]);
                accD[d] = fmaf(xv[u], wdp[d], accD[d]);
            }
        }
        xc += 8L * HWs;
    }

    if (valid) {
        float* bp = bn + (long)p * DD * NPOS + j;
        float* dp = dn + (long)p * DD * NPOS + j;
        #pragma unroll
        for (int d = 0; d < DD; ++d) {
            bp[(long)d * NPOS] = accB[d];
            dp[(long)d * NPOS] = accD[d];
        }
    }
}

// ---- kernel B1: partial S = Bn^T Dn (+ mB/mD partial sums) per (patch, j-eighth).
// grid (8, 72), 256 thr; thread owns a 2x2 (d,e) tile. LDS stride 34 => no bank
// conflicts on float2 reads.
#define B1_TJ 56
__global__ __launch_bounds__(256) void kB1(const float* __restrict__ bn,
                                           const float* __restrict__ dn,
                                           float* __restrict__ spart,
                                           float* __restrict__ mbp,
                                           float* __restrict__ mdp) {
    const int qb = blockIdx.x;  // 0..7
    const int p  = blockIdx.y;
    const int t  = threadIdx.x;
    const int j0 = qb * 392;    // 8 * 392 = 3136
    __shared__ float Bt[B1_TJ][34];
    __shared__ float Dt[B1_TJ][34];
    const int d2 = (t >> 4) << 1;   // 0,2,...,30
    const int e2 = (t & 15) << 1;   // 0,2,...,30
    float a00 = 0, a01 = 0, a10 = 0, a11 = 0;
    float mb0 = 0, mb1 = 0, md0 = 0, md1 = 0;

    const long pbase = (long)p * DD * NPOS;
    for (int tt = 0; tt < 7; ++tt) {
        const int jt = j0 + tt * B1_TJ;
        __syncthreads();
        for (int i = t; i < B1_TJ * DD; i += 256) {
            const int d  = i / B1_TJ;
            const int jj = i % B1_TJ;
            Bt[jj][d] = bn[pbase + (long)d * NPOS + jt + jj];
            Dt[jj][d] = dn[pbase + (long)d * NPOS + jt + jj];
        }
        __syncthreads();
        #pragma unroll 4
        for (int jj = 0; jj < B1_TJ; ++jj) {
            const float2 bv = *(const float2*)&Bt[jj][d2];
            const float2 dv = *(const float2*)&Dt[jj][e2];
            a00 = fmaf(bv.x, dv.x, a00);
            a01 = fmaf(bv.x, dv.y, a01);
            a10 = fmaf(bv.y, dv.x, a10);
            a11 = fmaf(bv.y, dv.y, a11);
            if (e2 == 0) { mb0 += bv.x; mb1 += bv.y; }
            if (d2 == 0) { md0 += dv.x; md1 += dv.y; }
        }
    }

    float* sp = spart + (long)(p * 8 + qb) * 1024;
    sp[(d2    ) * DD + e2    ] = a00;
    sp[(d2    ) * DD + e2 + 1] = a01;
    sp[(d2 + 1) * DD + e2    ] = a10;
    sp[(d2 + 1) * DD + e2 + 1] = a11;
    if (e2 == 0) { mbp[(p * 8 + qb) * DD + d2] = mb0; mbp[(p * 8 + qb) * DD + d2 + 1] = mb1; }
    if (d2 == 0) { mdp[(p * 8 + qb) * DD + e2] = md0; mdp[(p * 8 + qb) * DD + e2 + 1] = md1; }
}

// ---- kernel B2: reduce partials -> T -> G, h. grid (72), 256 thr.
__global__ __launch_bounds__(256) void kB2(const float* __restrict__ wphi,
                                           const float* __restrict__ spart,
                                           const float* __restrict__ mbp,
                                           const float* __restrict__ mdp,
                                           float* __restrict__ gout,
                                           float* __restrict__ hout) {
    const int p = blockIdx.x;
    const int t = threadIdx.x;
    __shared__ float Tm[DD][DD + 1];
    __shared__ float mbs[DD], mds[DD];

    if (t < DD) {
        float s1 = 0, s2 = 0;
        for (int q = 0; q < 8; ++q) {
            s1 += mbp[(p * 8 + q) * DD + t];
            s2 += mdp[(p * 8 + q) * DD + t];
        }
        mbs[t] = s1; mds[t] = s2;
    }
    __syncthreads();

    const float invn = 1.0f / (float)NPOS;
    {
        float4 s = make_float4(0.f, 0.f, 0.f, 0.f);
        for (int q = 0; q < 8; ++q) {
            const float4 v = *(const float4*)&spart[(long)(p * 8 + q) * 1024 + t * 4];
            s.x += v.x; s.y += v.y; s.z += v.z; s.w += v.w;
        }
        const int idx = t * 4;
        const int d = idx >> 5;
        const int e = idx & 31;
        const float mbd = mbs[d] * invn;
        Tm[d][e    ] = s.x * invn - mbd * (mds[e    ] * invn);
        Tm[d][e + 1] = s.y * invn - mbd * (mds[e + 1] * invn);
        Tm[d][e + 2] = s.z * invn - mbd * (mds[e + 2] * invn);
        Tm[d][e + 3] = s.w * invn - mbd * (mds[e + 3] * invn);
    }
    __syncthreads();

    // per-thread: one output channel c
    const int c = t;
    float wp[DD];
    #pragma unroll
    for (int e = 0; e < DD; ++e) wp[e] = wphi[c * DD + e];
    float h = 0.f;
    float* gp = gout + ((long)p * CC + c) * DD;
    #pragma unroll 4
    for (int d = 0; d < DD; ++d) {
        float g = 0.f;
        #pragma unroll
        for (int e = 0; e < DD; ++e) g = fmaf(wp[e], Tm[d][e], g);
        gp[d] = g;
        h = fmaf(mbs[d] * invn, g, h);
    }
    hout[p * CC + c] = h;
}

// ---- kernel C: out = x + Bn*G^T - h. grid (13, 72), 256 thr.
// Same 8-deep x staging as kA; Bn row in 32 VGPRs; G/h rows block-uniform
// (s_load); x/out coalesced; stores interleave with next FMA burst.
__global__ __launch_bounds__(256) void kC(const float* __restrict__ x,
                                          const float* __restrict__ bn,
                                          const float* __restrict__ gbuf,
                                          const float* __restrict__ hbuf,
                                          float* __restrict__ out) {
    const int jb = blockIdx.x;
    const int p  = blockIdx.y;
    const int t  = threadIdx.x;
    const int j  = jb * 256 + t;
    const bool valid = j < NPOS;
    const int jc = valid ? j : (NPOS - 1);
    const int b  = p / 9;
    const int gy = (p % 9) / 3;
    const int gx = p % 3;
    const int iy = jc / PH;
    const int ix = jc % PH;
    const long base = (long)b * CC * HWs + (long)(gy * PH + iy) * WWs + (gx * PH + ix);

    float bnv[DD];
    const float* bp = bn + (long)p * DD * NPOS + jc;
    #pragma unroll
    for (int d = 0; d < DD; ++d) bnv[d] = bp[(long)d * NPOS];

    const float* gp = gbuf + (long)p * CC * DD;
    const float* hp = hbuf + p * CC;
    const float* xc = x + base;
    float* oc = out + base;
    #pragma unroll 1
    for (int c0 = 0; c0 < CC; c0 += 8) {
        float xv[8];
        #pragma unroll
        for (int u = 0; u < 8; ++u) xv[u] = xc[(long)u * HWs];
        #pragma unroll
        for (int u = 0; u < 8; ++u) {
            float acc = -hp[c0 + u];
            const float* g = gp + (c0 + u) * DD;
            #pragma unroll
            for (int d = 0; d < DD; ++d) acc = fmaf(bnv[d], g[d], acc);
            if (valid) oc[(long)u * HWs] = xv[u] + acc;
        }
        xc += 8L * HWs;
        oc += 8L * HWs;
    }
}

extern "C" void kernel_launch(void* const* d_in, const int* in_sizes, int n_in,
                              void* d_out, int out_size, void* d_ws, size_t ws_size,
                              hipStream_t stream) {
    const float* x    = (const float*)d_in[0];
    const float* wb   = (const float*)d_in[1];
    const float* wd   = (const float*)d_in[2];
    const float* wphi = (const float*)d_in[3];
    float* ws = (float*)d_ws;

    float* wbt = ws + OFF_WBT;
    float* wdt = ws + OFF_WDT;
    float* bnp = ws + OFF_BN;
    float* dnp = ws + OFF_DN;
    float* sp  = ws + OFF_SP;
    float* mbp = ws + OFF_MBP;
    float* mdp = ws + OFF_MDP;
    float* gb  = ws + OFF_G;
    float* hb  = ws + OFF_H;

    hipLaunchKernelGGL(ktrans, dim3(1), dim3(256), 0, stream, wb, wd, wbt, wdt);
    hipLaunchKernelGGL(kA, dim3(13, 72), dim3(256), 0, stream, x, wbt, wdt, bnp, dnp);
    hipLaunchKernelGGL(kB1, dim3(8, 72), dim3(256), 0, stream, bnp, dnp, sp, mbp, mdp);
    hipLaunchKernelGGL(kB2, dim3(72), dim3(256), 0, stream, wphi, sp, mbp, mdp, gb, hb);
    hipLaunchKernelGGL(kC, dim3(13, 72), dim3(256), 0, stream, x, bnp, gb, hb, (float*)d_out);
}